// Round 5
// baseline (333.420 us; speedup 1.0000x reference)
//
#include <hip/hip_runtime.h>

// MultiPropMLP on MI355X: N=1M samples, MLP 16->64->64->1, per-sample weight
// set k in [0,8) via idxs (fp32 buffers, values bf16-rounded).
// Round 8 (resubmit): T-form MLP (verified R6/R7) + latency-regime levers:
//  - __launch_bounds__(256,8): VGPR<=64 -> 8 waves/SIMD eligible; LDS 20KB ->
//    7-8 blocks/CU resident (was ~10 waves/CU measured). TLP hides the per-step
//    L1 weight re-streams the compiler already chose (VGPR=60 last round).
//  - v_cvt_pk_bf16_f32 (RNE) replaces 3-op pack_rnd in both layer transitions:
//    -32 VALU instrs/step on the critical chain.
//  - b2 folded into layer-2 MFMA C-in.

typedef __attribute__((ext_vector_type(8))) short bfrag;   // 8 bf16 (4 VGPRs)
typedef __attribute__((ext_vector_type(4))) float ffrag;   // 4 fp32 acc

#define SPAN        512
#define NSPANS      2048
#define IMG_STRIDE  15360     // W0A 4096 | W1A 8192 | W2A 2048 | bias f32[65]
#define WS_NEED     ((size_t)(8 * IMG_STRIDE))

__device__ __forceinline__ unsigned short bf16r(float f) {
    unsigned int u = __float_as_uint(f);
    u += 0x7fffu + ((u >> 16) & 1u);
    return (unsigned short)(u >> 16);
}
// pack two fp32 (already exact bf16) -> u32 via byte-perm (truncation exact)
__device__ __forceinline__ unsigned int pack_trunc(float hiF, float loF) {
    return __builtin_amdgcn_perm(__float_as_uint(hiF), __float_as_uint(loF), 0x07060302u);
}
// packed f32x2 -> bf16x2 (RNE), lo in low half
__device__ __forceinline__ unsigned int cvtpk(float lo, float hi) {
    unsigned int r;
    asm("v_cvt_pk_bf16_f32 %0, %1, %2" : "=v"(r) : "v"(lo), "v"(hi));
    return r;
}
__device__ __forceinline__ bfrag mkfrag(unsigned int a, unsigned int b,
                                        unsigned int c, unsigned int d) {
    union { unsigned int u[4]; bfrag f; } x;
    x.u[0] = a; x.u[1] = b; x.u[2] = c; x.u[3] = d;
    return x.f;
}

// ---------- K0: per-k weight images (T-form, MFMA A-fragment order) ----------
// 64 blocks: k = bid>>3, part p = bid&7 (8-way split of each image).
// A-frag layout per mfma: element(lane, j) = A[row = lane&15][k-slot q*8+j].
// sigma(s,q,j) = s*32 + (j<4 ? q*4+j : 16 + q*4 + (j-4))  (bijection on [32s,32s+32))
// W0A @0    : [4 nt][64 lane][8 j] bf16 = W0t[h'=nt*16+l15][d=q*8+j] for q<2;
//             (q==2, j==0/1) = hi/lo bf16 split of b0[h'] (pairs with const-1 B lanes)
// W1A @4096 : [4 nt][2 s][64 lane][8 j] = W1t[h'=nt*16+l15][sigma(s,q,j)]
// W2A @12288: [2 s][64 lane][8 j] = (l15==0) ? W2t[0][sigma(s,q,j)] : 0
// bias @14336: f32 b1[64] | b2
__global__ void k_build_images(const float* __restrict__ W0, const float* __restrict__ b0,
                               const float* __restrict__ W1, const float* __restrict__ b1,
                               const float* __restrict__ W2, const float* __restrict__ b2,
                               unsigned char* __restrict__ wsB) {
    const int k = blockIdx.x >> 3, p = blockIdx.x & 7, t = threadIdx.x;
    unsigned char* img = wsB + k * IMG_STRIDE;
    unsigned short* w0a = (unsigned short*)img;
    unsigned short* w1a = (unsigned short*)(img + 4096);
    unsigned short* w2a = (unsigned short*)(img + 12288);
    float* bias = (float*)(img + 14336);
    {   // w0a: 2048 elems, 256 per part
        int e = p * 256 + t;
        int j = e & 7, lane = (e >> 3) & 63, nt = e >> 9, q = lane >> 4, l15 = lane & 15;
        unsigned short v = 0;
        if (q < 2) {
            v = bf16r(W0[k * 1024 + (q * 8 + j) * 64 + nt * 16 + l15]);
        } else if (q == 2 && j < 2) {
            float b = b0[k * 64 + nt * 16 + l15];
            unsigned short hb = bf16r(b);
            if (j == 0) v = hb;
            else        v = bf16r(b - __uint_as_float((unsigned int)hb << 16));
        }
        w0a[e] = v;
    }
    #pragma unroll
    for (int i = 0; i < 2; ++i) {   // w1a: 4096 elems, 512 per part
        int e = p * 512 + i * 256 + t;
        int j = e & 7, lane = (e >> 3) & 63, s = (e >> 9) & 1, nt = e >> 10;
        int q = lane >> 4, l15 = lane & 15;
        int h = s * 32 + ((j < 4) ? (q * 4 + j) : (16 + q * 4 + (j - 4)));
        w1a[e] = bf16r(W1[k * 4096 + h * 64 + nt * 16 + l15]);
    }
    if (t < 128) {   // w2a: 1024 elems, 128 per part
        int e = p * 128 + t;
        int j = e & 7, lane = (e >> 3) & 63, s = e >> 9, q = lane >> 4, l15 = lane & 15;
        int h = s * 32 + ((j < 4) ? (q * 4 + j) : (16 + q * 4 + (j - 4)));
        w2a[e] = (l15 == 0) ? bf16r(W2[k * 64 + h]) : (unsigned short)0;
    }
    if (p == 0) {
        if (t < 64) bias[t] = b1[k * 64 + t];
        else if (t == 64) bias[64] = b2[k];
    }
}

// ---------- K1: fused sort + gather + T-form MFMA MLP, one 512-sample span/block ----------
__global__ __launch_bounds__(256, 8) void k_fused(const int* __restrict__ idxs,
                                                  const float* __restrict__ xs,
                                                  const unsigned char* __restrict__ wsB,
                                                  float* __restrict__ out) {
    __shared__ int wcnt[2][4][8];
    __shared__ int bsbase[2][4][8];
    __shared__ int cntS[8], startS[8];
    __shared__ unsigned short sId[SPAN];                       // 1 KB
    __shared__ __align__(16) unsigned short Xg[SPAN * 16];     // 16 KB  [g][q][m][8]
    __shared__ float outBuf[SPAN];                             // 2 KB

    const int tid = threadIdx.x, lane = tid & 63, w = tid >> 6;
    const int q = lane >> 4, l15 = lane & 15;
    const int base = blockIdx.x * SPAN;

    // ---- phase S: block-local counting sort (ballot ranks, stable) ----
    int kreg[2], lrank[2];
    #pragma unroll
    for (int it = 0; it < 2; ++it) {
        int k = idxs[base + it * 256 + tid];
        kreg[it] = k;
        unsigned long long mymask = 0;
        #pragma unroll
        for (int kk = 0; kk < 8; ++kk) {
            unsigned long long m = __ballot(k == kk);
            if (k == kk) mymask = m;
            if (lane == 0) wcnt[it][w][kk] = (int)__popcll(m);
        }
        lrank[it] = (int)__popcll(mymask & ((1ull << lane) - 1ull));
    }
    __syncthreads();
    if (tid < 8) {
        int c = 0;
        for (int it = 0; it < 2; ++it)
            for (int w2 = 0; w2 < 4; ++w2) c += wcnt[it][w2][tid];
        cntS[tid] = c;
    }
    __syncthreads();
    if (tid == 0) {
        int s = 0;
        for (int k = 0; k < 8; ++k) { startS[k] = s; s += cntS[k]; }
    }
    __syncthreads();
    if (tid < 64) {
        int it = tid >> 5, w2 = (tid >> 3) & 3, kk = tid & 7;
        int b = startS[kk];
        for (int it2 = 0; it2 < it; ++it2)
            for (int w3 = 0; w3 < 4; ++w3) b += wcnt[it2][w3][kk];
        for (int w3 = 0; w3 < w2; ++w3) b += wcnt[it][w3][kk];
        bsbase[it][w2][kk] = b;
    }
    __syncthreads();
    #pragma unroll
    for (int it = 0; it < 2; ++it)
        sId[bsbase[it][w][kreg[it]] + lrank[it]] = (unsigned short)(it * 256 + tid);
    __syncthreads();

    // ---- phase G: gather X rows in sorted order, pack bf16 frag layout ----
    #pragma unroll
    for (int it = 0; it < 2; ++it) {
        const int r = it * 256 + tid;
        const int gid = base + (int)sId[r];
        const float4* p = (const float4*)(xs + (size_t)gid * 16);
        float4 f0 = p[0], f1 = p[1], f2 = p[2], f3 = p[3];
        uint4 lo, hi;
        lo.x = pack_trunc(f0.y, f0.x); lo.y = pack_trunc(f0.w, f0.z);
        lo.z = pack_trunc(f1.y, f1.x); lo.w = pack_trunc(f1.w, f1.z);
        hi.x = pack_trunc(f2.y, f2.x); hi.y = pack_trunc(f2.w, f2.z);
        hi.z = pack_trunc(f3.y, f3.x); hi.w = pack_trunc(f3.w, f3.z);
        const int g = r >> 4, m = r & 15;
        *(uint4*)(Xg + g * 256 + m * 8)       = lo;   // q=0 chunk (d 0..7)
        *(uint4*)(Xg + g * 256 + 128 + m * 8) = hi;   // q=1 chunk (d 8..15)
    }
    __syncthreads();

    // ---- phase M: wave w processes buckets k = w, w+4 (weights as A, no LDS) ----
    #pragma unroll
    for (int kk2 = 0; kk2 < 2; ++kk2) {
        const int k = w + kk2 * 4;
        const int cnt = cntS[k];
        if (cnt == 0) continue;
        const int start = startS[k];
        const unsigned char* img = wsB + k * IMG_STRIDE;

        bfrag w0f[4], w1f[4][2], w2f[2];
        #pragma unroll
        for (int nt = 0; nt < 4; ++nt)
            w0f[nt] = *(const bfrag*)(img + nt * 1024 + lane * 16);
        #pragma unroll
        for (int nt = 0; nt < 4; ++nt)
            #pragma unroll
            for (int s = 0; s < 2; ++s)
                w1f[nt][s] = *(const bfrag*)(img + 4096 + ((nt * 2 + s) * 64 + lane) * 16);
        #pragma unroll
        for (int s = 0; s < 2; ++s)
            w2f[s] = *(const bfrag*)(img + 12288 + (s * 64 + lane) * 16);
        const float* bias = (const float*)(img + 14336);
        ffrag b1v[4];
        #pragma unroll
        for (int nt = 0; nt < 4; ++nt)
            b1v[nt] = *(const ffrag*)(bias + nt * 16 + q * 4);   // b1[nt*16+q*4+r]
        // b2 folded into layer-2 C-in: row 0 lives at (q==0, reg 0)
        ffrag c2 = {0.f, 0.f, 0.f, 0.f};
        if (q == 0) c2[0] = bias[64];

        const int nst = (cnt + 15) >> 4;

        // Branchless B-frag load: col = l15 = sample-in-step; k-slot q*8+j = d
        // for q<2. q=2 lanes read chunk-0 garbage (finite bf16 x-data) then get
        // 1.0 forced into slots 16/17 (bias channel); garbage elsewhere meets
        // exact-0 A weights (0*finite = 0). q=3 reads chunk-1 garbage, all-zero A.
        auto loadB = [&](int st) -> bfrag {
            int r = start + st * 16 + l15;
            int rm = start + cnt - 1;
            r = r < rm ? r : rm;
            bfrag bv = *(const bfrag*)(Xg + (r >> 4) * 256 + (q & 1) * 128 + (r & 15) * 8);
            if (q == 2) { bv[0] = (short)0x3F80; bv[1] = (short)0x3F80; }
            return bv;
        };

        // Branchless full 3-layer chain for one 16-sample step; returns D-frag.
        auto chain = [&](bfrag bv) -> ffrag {
            ffrag acc0[4];
            #pragma unroll
            for (int nt = 0; nt < 4; ++nt) {
                ffrag z = {0.f, 0.f, 0.f, 0.f};
                acc0[nt] = __builtin_amdgcn_mfma_f32_16x16x32_bf16(w0f[nt], bv, z, 0, 0, 0);
            }
            unsigned int P[8];
            #pragma unroll
            for (int nt = 0; nt < 4; ++nt) {
                float v0 = acc0[nt][0] > 0.f ? acc0[nt][0] : 0.f;
                float v1 = acc0[nt][1] > 0.f ? acc0[nt][1] : 0.f;
                float v2 = acc0[nt][2] > 0.f ? acc0[nt][2] : 0.f;
                float v3 = acc0[nt][3] > 0.f ? acc0[nt][3] : 0.f;
                P[nt * 2]     = cvtpk(v0, v1);
                P[nt * 2 + 1] = cvtpk(v2, v3);
            }
            bfrag h10 = mkfrag(P[0], P[1], P[2], P[3]);   // s=0: h in [0,32)
            bfrag h11 = mkfrag(P[4], P[5], P[6], P[7]);   // s=1: h in [32,64)
            ffrag acc1[4];
            #pragma unroll
            for (int nt = 0; nt < 4; ++nt) {
                acc1[nt] = __builtin_amdgcn_mfma_f32_16x16x32_bf16(w1f[nt][0], h10, b1v[nt], 0, 0, 0);
                acc1[nt] = __builtin_amdgcn_mfma_f32_16x16x32_bf16(w1f[nt][1], h11, acc1[nt], 0, 0, 0);
            }
            unsigned int Qp[8];
            #pragma unroll
            for (int nt = 0; nt < 4; ++nt) {
                float v0 = acc1[nt][0] > 0.f ? acc1[nt][0] : 0.f;
                float v1 = acc1[nt][1] > 0.f ? acc1[nt][1] : 0.f;
                float v2 = acc1[nt][2] > 0.f ? acc1[nt][2] : 0.f;
                float v3 = acc1[nt][3] > 0.f ? acc1[nt][3] : 0.f;
                Qp[nt * 2]     = cvtpk(v0, v1);
                Qp[nt * 2 + 1] = cvtpk(v2, v3);
            }
            bfrag h20 = mkfrag(Qp[0], Qp[1], Qp[2], Qp[3]);
            bfrag h21 = mkfrag(Qp[4], Qp[5], Qp[6], Qp[7]);
            ffrag d = __builtin_amdgcn_mfma_f32_16x16x32_bf16(w2f[0], h20, c2, 0, 0, 0);
            d = __builtin_amdgcn_mfma_f32_16x16x32_bf16(w2f[1], h21, d, 0, 0, 0);
            return d;
        };

        // 2-way interleaved steps: chains st / st+1 are independent -> 2x ILP.
        int st = 0;
        bfrag bA = loadB(0);
        bfrag bB = loadB(1);
        for (; st + 1 < nst; st += 2) {
            bfrag pA = loadB(st + 2);
            bfrag pB = loadB(st + 3);
            ffrag dA = chain(bA);
            ffrag dB = chain(bB);
            if (q == 0) {
                int rowA = st * 16 + l15;
                if (rowA < cnt) outBuf[sId[start + rowA]] = dA[0];
                int rowB = (st + 1) * 16 + l15;
                if (rowB < cnt) outBuf[sId[start + rowB]] = dB[0];
            }
            bA = pA; bB = pB;
        }
        if (st < nst) {
            ffrag dA = chain(bA);
            if (q == 0) {
                int row = st * 16 + l15;
                if (row < cnt) outBuf[sId[start + row]] = dA[0];
            }
        }
    }
    __syncthreads();

    // ---- phase O: coalesced out write (512 floats) ----
    ((float2*)(out + base))[tid] = ((const float2*)outBuf)[tid];
}

// ---------- fallback: per-thread fp32 ----------
__global__ void k_fallback(const int* __restrict__ idxs, const float* __restrict__ xs,
                           const float* __restrict__ W0, const float* __restrict__ b0,
                           const float* __restrict__ W1, const float* __restrict__ b1,
                           const float* __restrict__ W2, const float* __restrict__ b2,
                           float* __restrict__ out, int N) {
    int n = blockIdx.x * blockDim.x + threadIdx.x;
    if (n >= N) return;
    int k = idxs[n];
    float h0[64];
    #pragma unroll
    for (int j = 0; j < 64; ++j) h0[j] = b0[k * 64 + j];
    for (int i = 0; i < 16; ++i) {
        float xi = xs[(size_t)n * 16 + i];
        #pragma unroll
        for (int j = 0; j < 64; ++j) h0[j] = fmaf(xi, W0[k * 1024 + i * 64 + j], h0[j]);
    }
    #pragma unroll
    for (int j = 0; j < 64; ++j) h0[j] = fmaxf(h0[j], 0.f);
    float acc = b2[k];
    for (int jc = 0; jc < 4; ++jc) {
        float h1[16];
        #pragma unroll
        for (int j = 0; j < 16; ++j) h1[j] = b1[k * 64 + jc * 16 + j];
        for (int i = 0; i < 64; ++i) {
            float hv = h0[i];
            #pragma unroll
            for (int j = 0; j < 16; ++j)
                h1[j] = fmaf(hv, W1[k * 4096 + i * 64 + jc * 16 + j], h1[j]);
        }
        #pragma unroll
        for (int j = 0; j < 16; ++j) acc = fmaf(fmaxf(h1[j], 0.f), W2[k * 64 + jc * 16 + j], acc);
    }
    out[n] = acc;
}

extern "C" void kernel_launch(void* const* d_in, const int* in_sizes, int n_in,
                              void* d_out, int out_size, void* d_ws, size_t ws_size,
                              hipStream_t stream) {
    const int*   idxs = (const int*)d_in[0];
    const float* xs   = (const float*)d_in[1];
    const float* W0   = (const float*)d_in[2];
    const float* b0   = (const float*)d_in[3];
    const float* W1   = (const float*)d_in[4];
    const float* b1   = (const float*)d_in[5];
    const float* W2   = (const float*)d_in[6];
    const float* b2   = (const float*)d_in[7];
    float* out = (float*)d_out;
    const int N = in_sizes[0];  // 1,048,576

    if (N != SPAN * NSPANS || ws_size < WS_NEED) {
        k_fallback<<<(N + 255) / 256, 256, 0, stream>>>(idxs, xs, W0, b0, W1, b1, W2, b2, out, N);
        return;
    }

    unsigned char* wsB = (unsigned char*)d_ws;
    k_build_images<<<64, 256, 0, stream>>>(W0, b0, W1, b1, W2, b2, wsB);
    k_fused<<<NSPANS, 256, 0, stream>>>(idxs, xs, wsB, out);
}

// Round 10
// 127.011 us; speedup vs baseline: 2.6251x; 2.6251x over previous
//
#include <hip/hip_runtime.h>

// MultiPropMLP on MI355X: N=1M samples, MLP 16->64->64->1, per-sample weight
// set k in [0,8) via idxs (fp32 buffers, values bf16-rounded).
// Round 9 (resubmit x4): T-form MLP. R8's (256,8) cap spilled (VGPR=32, 350MB
// scratch writes, 246us). Root cause confirmed: natural live state ~140 VGPR
// (14 weight frags + b1v + 2 chains). This round: __launch_bounds__(256,2) ->
// VGPR cap 256 so weights stay RESIDENT across the bucket loop; inner loop has
// zero memory ops. cvt_pk_bf16_f32 pack + b2-in-C fold kept (HW-verified R8).

typedef __attribute__((ext_vector_type(8))) short bfrag;   // 8 bf16 (4 VGPRs)
typedef __attribute__((ext_vector_type(4))) float ffrag;   // 4 fp32 acc

#define SPAN        512
#define NSPANS      2048
#define IMG_STRIDE  15360     // W0A 4096 | W1A 8192 | W2A 2048 | bias f32[65]
#define WS_NEED     ((size_t)(8 * IMG_STRIDE))

__device__ __forceinline__ unsigned short bf16r(float f) {
    unsigned int u = __float_as_uint(f);
    u += 0x7fffu + ((u >> 16) & 1u);
    return (unsigned short)(u >> 16);
}
// pack two fp32 (already exact bf16) -> u32 via byte-perm (truncation exact)
__device__ __forceinline__ unsigned int pack_trunc(float hiF, float loF) {
    return __builtin_amdgcn_perm(__float_as_uint(hiF), __float_as_uint(loF), 0x07060302u);
}
// packed f32x2 -> bf16x2 (RNE), lo in low half
__device__ __forceinline__ unsigned int cvtpk(float lo, float hi) {
    unsigned int r;
    asm("v_cvt_pk_bf16_f32 %0, %1, %2" : "=v"(r) : "v"(lo), "v"(hi));
    return r;
}
__device__ __forceinline__ bfrag mkfrag(unsigned int a, unsigned int b,
                                        unsigned int c, unsigned int d) {
    union { unsigned int u[4]; bfrag f; } x;
    x.u[0] = a; x.u[1] = b; x.u[2] = c; x.u[3] = d;
    return x.f;
}

// ---------- K0: per-k weight images (T-form, MFMA A-fragment order) ----------
// 64 blocks: k = bid>>3, part p = bid&7 (8-way split of each image).
// A-frag layout per mfma: element(lane, j) = A[row = lane&15][k-slot q*8+j].
// sigma(s,q,j) = s*32 + (j<4 ? q*4+j : 16 + q*4 + (j-4))  (bijection on [32s,32s+32))
// W0A @0    : [4 nt][64 lane][8 j] bf16 = W0t[h'=nt*16+l15][d=q*8+j] for q<2;
//             (q==2, j==0/1) = hi/lo bf16 split of b0[h'] (pairs with const-1 B lanes)
// W1A @4096 : [4 nt][2 s][64 lane][8 j] = W1t[h'=nt*16+l15][sigma(s,q,j)]
// W2A @12288: [2 s][64 lane][8 j] = (l15==0) ? W2t[0][sigma(s,q,j)] : 0
// bias @14336: f32 b1[64] | b2
__global__ void k_build_images(const float* __restrict__ W0, const float* __restrict__ b0,
                               const float* __restrict__ W1, const float* __restrict__ b1,
                               const float* __restrict__ W2, const float* __restrict__ b2,
                               unsigned char* __restrict__ wsB) {
    const int k = blockIdx.x >> 3, p = blockIdx.x & 7, t = threadIdx.x;
    unsigned char* img = wsB + k * IMG_STRIDE;
    unsigned short* w0a = (unsigned short*)img;
    unsigned short* w1a = (unsigned short*)(img + 4096);
    unsigned short* w2a = (unsigned short*)(img + 12288);
    float* bias = (float*)(img + 14336);
    {   // w0a: 2048 elems, 256 per part
        int e = p * 256 + t;
        int j = e & 7, lane = (e >> 3) & 63, nt = e >> 9, q = lane >> 4, l15 = lane & 15;
        unsigned short v = 0;
        if (q < 2) {
            v = bf16r(W0[k * 1024 + (q * 8 + j) * 64 + nt * 16 + l15]);
        } else if (q == 2 && j < 2) {
            float b = b0[k * 64 + nt * 16 + l15];
            unsigned short hb = bf16r(b);
            if (j == 0) v = hb;
            else        v = bf16r(b - __uint_as_float((unsigned int)hb << 16));
        }
        w0a[e] = v;
    }
    #pragma unroll
    for (int i = 0; i < 2; ++i) {   // w1a: 4096 elems, 512 per part
        int e = p * 512 + i * 256 + t;
        int j = e & 7, lane = (e >> 3) & 63, s = (e >> 9) & 1, nt = e >> 10;
        int q = lane >> 4, l15 = lane & 15;
        int h = s * 32 + ((j < 4) ? (q * 4 + j) : (16 + q * 4 + (j - 4)));
        w1a[e] = bf16r(W1[k * 4096 + h * 64 + nt * 16 + l15]);
    }
    if (t < 128) {   // w2a: 1024 elems, 128 per part
        int e = p * 128 + t;
        int j = e & 7, lane = (e >> 3) & 63, s = e >> 9, q = lane >> 4, l15 = lane & 15;
        int h = s * 32 + ((j < 4) ? (q * 4 + j) : (16 + q * 4 + (j - 4)));
        w2a[e] = (l15 == 0) ? bf16r(W2[k * 64 + h]) : (unsigned short)0;
    }
    if (p == 0) {
        if (t < 64) bias[t] = b1[k * 64 + t];
        else if (t == 64) bias[64] = b2[k];
    }
}

// ---------- K1: fused sort + gather + T-form MFMA MLP, one 512-sample span/block ----------
__global__ __launch_bounds__(256, 2) void k_fused(const int* __restrict__ idxs,
                                                  const float* __restrict__ xs,
                                                  const unsigned char* __restrict__ wsB,
                                                  float* __restrict__ out) {
    __shared__ int wcnt[2][4][8];
    __shared__ int bsbase[2][4][8];
    __shared__ int cntS[8], startS[8];
    __shared__ unsigned short sId[SPAN];                       // 1 KB
    __shared__ __align__(16) unsigned short Xg[SPAN * 16];     // 16 KB  [g][q][m][8]
    __shared__ float outBuf[SPAN];                             // 2 KB

    const int tid = threadIdx.x, lane = tid & 63, w = tid >> 6;
    const int q = lane >> 4, l15 = lane & 15;
    const int base = blockIdx.x * SPAN;

    // ---- phase S: block-local counting sort (ballot ranks, stable) ----
    int kreg[2], lrank[2];
    #pragma unroll
    for (int it = 0; it < 2; ++it) {
        int k = idxs[base + it * 256 + tid];
        kreg[it] = k;
        unsigned long long mymask = 0;
        #pragma unroll
        for (int kk = 0; kk < 8; ++kk) {
            unsigned long long m = __ballot(k == kk);
            if (k == kk) mymask = m;
            if (lane == 0) wcnt[it][w][kk] = (int)__popcll(m);
        }
        lrank[it] = (int)__popcll(mymask & ((1ull << lane) - 1ull));
    }
    __syncthreads();
    if (tid < 8) {
        int c = 0;
        for (int it = 0; it < 2; ++it)
            for (int w2 = 0; w2 < 4; ++w2) c += wcnt[it][w2][tid];
        cntS[tid] = c;
    }
    __syncthreads();
    if (tid == 0) {
        int s = 0;
        for (int k = 0; k < 8; ++k) { startS[k] = s; s += cntS[k]; }
    }
    __syncthreads();
    if (tid < 64) {
        int it = tid >> 5, w2 = (tid >> 3) & 3, kk = tid & 7;
        int b = startS[kk];
        for (int it2 = 0; it2 < it; ++it2)
            for (int w3 = 0; w3 < 4; ++w3) b += wcnt[it2][w3][kk];
        for (int w3 = 0; w3 < w2; ++w3) b += wcnt[it][w3][kk];
        bsbase[it][w2][kk] = b;
    }
    __syncthreads();
    #pragma unroll
    for (int it = 0; it < 2; ++it)
        sId[bsbase[it][w][kreg[it]] + lrank[it]] = (unsigned short)(it * 256 + tid);
    __syncthreads();

    // ---- phase G: gather X rows in sorted order, pack bf16 frag layout ----
    #pragma unroll
    for (int it = 0; it < 2; ++it) {
        const int r = it * 256 + tid;
        const int gid = base + (int)sId[r];
        const float4* p = (const float4*)(xs + (size_t)gid * 16);
        float4 f0 = p[0], f1 = p[1], f2 = p[2], f3 = p[3];
        uint4 lo, hi;
        lo.x = pack_trunc(f0.y, f0.x); lo.y = pack_trunc(f0.w, f0.z);
        lo.z = pack_trunc(f1.y, f1.x); lo.w = pack_trunc(f1.w, f1.z);
        hi.x = pack_trunc(f2.y, f2.x); hi.y = pack_trunc(f2.w, f2.z);
        hi.z = pack_trunc(f3.y, f3.x); hi.w = pack_trunc(f3.w, f3.z);
        const int g = r >> 4, m = r & 15;
        *(uint4*)(Xg + g * 256 + m * 8)       = lo;   // q=0 chunk (d 0..7)
        *(uint4*)(Xg + g * 256 + 128 + m * 8) = hi;   // q=1 chunk (d 8..15)
    }
    __syncthreads();

    // ---- phase M: wave w processes buckets k = w, w+4 (weights as A, no LDS) ----
    #pragma unroll
    for (int kk2 = 0; kk2 < 2; ++kk2) {
        const int k = w + kk2 * 4;
        const int cnt = cntS[k];
        if (cnt == 0) continue;
        const int start = startS[k];
        const unsigned char* img = wsB + k * IMG_STRIDE;

        bfrag w0f[4], w1f[4][2], w2f[2];
        #pragma unroll
        for (int nt = 0; nt < 4; ++nt)
            w0f[nt] = *(const bfrag*)(img + nt * 1024 + lane * 16);
        #pragma unroll
        for (int nt = 0; nt < 4; ++nt)
            #pragma unroll
            for (int s = 0; s < 2; ++s)
                w1f[nt][s] = *(const bfrag*)(img + 4096 + ((nt * 2 + s) * 64 + lane) * 16);
        #pragma unroll
        for (int s = 0; s < 2; ++s)
            w2f[s] = *(const bfrag*)(img + 12288 + (s * 64 + lane) * 16);
        const float* bias = (const float*)(img + 14336);
        ffrag b1v[4];
        #pragma unroll
        for (int nt = 0; nt < 4; ++nt)
            b1v[nt] = *(const ffrag*)(bias + nt * 16 + q * 4);   // b1[nt*16+q*4+r]
        // b2 folded into layer-2 C-in: row 0 lives at (q==0, reg 0)
        ffrag c2 = {0.f, 0.f, 0.f, 0.f};
        if (q == 0) c2[0] = bias[64];

        const int nst = (cnt + 15) >> 4;

        // Branchless B-frag load: col = l15 = sample-in-step; k-slot q*8+j = d
        // for q<2. q=2 lanes read chunk-0 garbage (finite bf16 x-data) then get
        // 1.0 forced into slots 16/17 (bias channel); garbage elsewhere meets
        // exact-0 A weights (0*finite = 0). q=3 reads chunk-1 garbage, all-zero A.
        auto loadB = [&](int st) -> bfrag {
            int r = start + st * 16 + l15;
            int rm = start + cnt - 1;
            r = r < rm ? r : rm;
            bfrag bv = *(const bfrag*)(Xg + (r >> 4) * 256 + (q & 1) * 128 + (r & 15) * 8);
            if (q == 2) { bv[0] = (short)0x3F80; bv[1] = (short)0x3F80; }
            return bv;
        };

        // Branchless full 3-layer chain for one 16-sample step; returns D-frag.
        auto chain = [&](bfrag bv) -> ffrag {
            ffrag acc0[4];
            #pragma unroll
            for (int nt = 0; nt < 4; ++nt) {
                ffrag z = {0.f, 0.f, 0.f, 0.f};
                acc0[nt] = __builtin_amdgcn_mfma_f32_16x16x32_bf16(w0f[nt], bv, z, 0, 0, 0);
            }
            unsigned int P[8];
            #pragma unroll
            for (int nt = 0; nt < 4; ++nt) {
                float v0 = acc0[nt][0] > 0.f ? acc0[nt][0] : 0.f;
                float v1 = acc0[nt][1] > 0.f ? acc0[nt][1] : 0.f;
                float v2 = acc0[nt][2] > 0.f ? acc0[nt][2] : 0.f;
                float v3 = acc0[nt][3] > 0.f ? acc0[nt][3] : 0.f;
                P[nt * 2]     = cvtpk(v0, v1);
                P[nt * 2 + 1] = cvtpk(v2, v3);
            }
            bfrag h10 = mkfrag(P[0], P[1], P[2], P[3]);   // s=0: h in [0,32)
            bfrag h11 = mkfrag(P[4], P[5], P[6], P[7]);   // s=1: h in [32,64)
            ffrag acc1[4];
            #pragma unroll
            for (int nt = 0; nt < 4; ++nt) {
                acc1[nt] = __builtin_amdgcn_mfma_f32_16x16x32_bf16(w1f[nt][0], h10, b1v[nt], 0, 0, 0);
                acc1[nt] = __builtin_amdgcn_mfma_f32_16x16x32_bf16(w1f[nt][1], h11, acc1[nt], 0, 0, 0);
            }
            unsigned int Qp[8];
            #pragma unroll
            for (int nt = 0; nt < 4; ++nt) {
                float v0 = acc1[nt][0] > 0.f ? acc1[nt][0] : 0.f;
                float v1 = acc1[nt][1] > 0.f ? acc1[nt][1] : 0.f;
                float v2 = acc1[nt][2] > 0.f ? acc1[nt][2] : 0.f;
                float v3 = acc1[nt][3] > 0.f ? acc1[nt][3] : 0.f;
                Qp[nt * 2]     = cvtpk(v0, v1);
                Qp[nt * 2 + 1] = cvtpk(v2, v3);
            }
            bfrag h20 = mkfrag(Qp[0], Qp[1], Qp[2], Qp[3]);
            bfrag h21 = mkfrag(Qp[4], Qp[5], Qp[6], Qp[7]);
            ffrag d = __builtin_amdgcn_mfma_f32_16x16x32_bf16(w2f[0], h20, c2, 0, 0, 0);
            d = __builtin_amdgcn_mfma_f32_16x16x32_bf16(w2f[1], h21, d, 0, 0, 0);
            return d;
        };

        // 2-way interleaved steps: chains st / st+1 are independent -> 2x ILP.
        int st = 0;
        bfrag bA = loadB(0);
        bfrag bB = loadB(1);
        for (; st + 1 < nst; st += 2) {
            bfrag pA = loadB(st + 2);
            bfrag pB = loadB(st + 3);
            ffrag dA = chain(bA);
            ffrag dB = chain(bB);
            if (q == 0) {
                int rowA = st * 16 + l15;
                if (rowA < cnt) outBuf[sId[start + rowA]] = dA[0];
                int rowB = (st + 1) * 16 + l15;
                if (rowB < cnt) outBuf[sId[start + rowB]] = dB[0];
            }
            bA = pA; bB = pB;
        }
        if (st < nst) {
            ffrag dA = chain(bA);
            if (q == 0) {
                int row = st * 16 + l15;
                if (row < cnt) outBuf[sId[start + row]] = dA[0];
            }
        }
    }
    __syncthreads();

    // ---- phase O: coalesced out write (512 floats) ----
    ((float2*)(out + base))[tid] = ((const float2*)outBuf)[tid];
}

// ---------- fallback: per-thread fp32 ----------
__global__ void k_fallback(const int* __restrict__ idxs, const float* __restrict__ xs,
                           const float* __restrict__ W0, const float* __restrict__ b0,
                           const float* __restrict__ W1, const float* __restrict__ b1,
                           const float* __restrict__ W2, const float* __restrict__ b2,
                           float* __restrict__ out, int N) {
    int n = blockIdx.x * blockDim.x + threadIdx.x;
    if (n >= N) return;
    int k = idxs[n];
    float h0[64];
    #pragma unroll
    for (int j = 0; j < 64; ++j) h0[j] = b0[k * 64 + j];
    for (int i = 0; i < 16; ++i) {
        float xi = xs[(size_t)n * 16 + i];
        #pragma unroll
        for (int j = 0; j < 64; ++j) h0[j] = fmaf(xi, W0[k * 1024 + i * 64 + j], h0[j]);
    }
    #pragma unroll
    for (int j = 0; j < 64; ++j) h0[j] = fmaxf(h0[j], 0.f);
    float acc = b2[k];
    for (int jc = 0; jc < 4; ++jc) {
        float h1[16];
        #pragma unroll
        for (int j = 0; j < 16; ++j) h1[j] = b1[k * 64 + jc * 16 + j];
        for (int i = 0; i < 64; ++i) {
            float hv = h0[i];
            #pragma unroll
            for (int j = 0; j < 16; ++j)
                h1[j] = fmaf(hv, W1[k * 4096 + i * 64 + jc * 16 + j], h1[j]);
        }
        #pragma unroll
        for (int j = 0; j < 16; ++j) acc = fmaf(fmaxf(h1[j], 0.f), W2[k * 64 + jc * 16 + j], acc);
    }
    out[n] = acc;
}

extern "C" void kernel_launch(void* const* d_in, const int* in_sizes, int n_in,
                              void* d_out, int out_size, void* d_ws, size_t ws_size,
                              hipStream_t stream) {
    const int*   idxs = (const int*)d_in[0];
    const float* xs   = (const float*)d_in[1];
    const float* W0   = (const float*)d_in[2];
    const float* b0   = (const float*)d_in[3];
    const float* W1   = (const float*)d_in[4];
    const float* b1   = (const float*)d_in[5];
    const float* W2   = (const float*)d_in[6];
    const float* b2   = (const float*)d_in[7];
    float* out = (float*)d_out;
    const int N = in_sizes[0];  // 1,048,576

    if (N != SPAN * NSPANS || ws_size < WS_NEED) {
        k_fallback<<<(N + 255) / 256, 256, 0, stream>>>(idxs, xs, W0, b0, W1, b1, W2, b2, out, N);
        return;
    }

    unsigned char* wsB = (unsigned char*)d_ws;
    k_build_images<<<64, 256, 0, stream>>>(W0, b0, W1, b1, W2, b2, wsB);
    k_fused<<<NSPANS, 256, 0, stream>>>(idxs, xs, wsB, out);
}